// Round 1
// baseline (167.760 us; speedup 1.0000x reference)
//
#include <hip/hip_runtime.h>

using f32x4   = __attribute__((ext_vector_type(4))) float;
using short8  = __attribute__((ext_vector_type(8))) short;
using ushort8 = __attribute__((ext_vector_type(8))) unsigned short;

#define DI __device__ __forceinline__

DI unsigned short f2bf(float f) {
    unsigned int u = __float_as_uint(f);
    unsigned int r = u + 0x7FFFu + ((u >> 16) & 1u);
    return (unsigned short)(r >> 16);
}

// ---- problem constants (fixed by setup_inputs) ----
constexpr int N_SEQ = 8192;
constexpr int QH    = 32;
constexpr int KH    = 2;
constexpr int D     = 128;
constexpr int M_CMP = 511;   // (8192-32)/16 + 1
constexpr int MP    = 512;   // padded M

// ============ Stage 1: block compress ============
// ck[m,h,d] = (sum_k (k[m*16+k,h,d] + pe_key[k,d]) * w_key[k]) / 32   (f32 -> d_out)
// also writes bf16 ckb[h][m][d] and transposed cvbT[h][d][m] into workspace.
__global__ __launch_bounds__(256)
void compress_kernel(const float* __restrict__ kin, const float* __restrict__ vin,
                     const float* __restrict__ w_key, const float* __restrict__ pe_key,
                     const float* __restrict__ w_val, const float* __restrict__ pe_val,
                     float* __restrict__ ck_out,
                     unsigned short* __restrict__ ckb,
                     unsigned short* __restrict__ cvbT)
{
    const int m  = blockIdx.x;      // 0..511 (511 is zero pad)
    const int t  = threadIdx.x;     // 0..255
    const int hh = t >> 7;          // kv head
    const int d  = t & 127;
    float acck = 0.f, accv = 0.f;
    if (m < M_CMP) {
        #pragma unroll
        for (int k = 0; k < 32; ++k) {
            float xk = kin[((m*16 + k)*KH + hh)*D + d];
            float xv = vin[((m*16 + k)*KH + hh)*D + d];
            acck += (xk + pe_key[k*D + d]) * w_key[k];
            accv += (xv + pe_val[k*D + d]) * w_val[k];
        }
        acck *= (1.f/32.f);
        accv *= (1.f/32.f);
        ck_out[(m*KH + hh)*D + d] = acck;
    }
    ckb[(hh*MP + m)*D + d]  = f2bf(acck);
    cvbT[(hh*D + d)*MP + m] = f2bf(accv);
}

// ============ Stage 2: flash attention over compressed KV ============
// block: 16 consecutive n  x  1 kv-head.  512 threads = 8 waves, 2 n per wave.
// MFMA tile rows = the 16 q-heads (G) of a single n  -> mask uniform per tile.
__global__ __launch_bounds__(512)
void attn_kernel(const float* __restrict__ q,
                 const unsigned short* __restrict__ ckb,
                 const unsigned short* __restrict__ cvbT,
                 float* __restrict__ o,
                 float* __restrict__ lse)
{
    // padded LDS tiles (pads chosen to keep 16B alignment and spread banks)
    __shared__ __align__(16) unsigned short ck_s[32][136];   // [m_local][d]
    __shared__ __align__(16) unsigned short cvT_s[128][40];  // [d][m_local]
    __shared__ __align__(16) unsigned short p_s[16][16][40]; // [wave*2+rt][g][m_local]

    const int n0   = blockIdx.x << 4;
    const int h    = blockIdx.y;
    const int t    = threadIdx.x;
    const int wid  = t >> 6;
    const int lane = t & 63;
    const int col  = lane & 15;   // MFMA col / A-row
    const int hi   = lane >> 4;   // lane quad

    const float sm_scale = 0.08838834764831845f; // 128^-0.5
    const float NEG_INF  = -__builtin_inff();

    // per-wave rows: rt in {0,1}, n = n0 + wid*2 + rt
    int nrow[2], mcnt[2];
    short8 qf[2][4];
    #pragma unroll
    for (int rt = 0; rt < 2; ++rt) {
        int n = n0 + wid*2 + rt;
        nrow[rt] = n;
        mcnt[rt] = (n >= 31) ? (((n - 31) >> 4) + 1) : 0;
        // A-frag: row = lane&15 (= head g), k(d) = kc*32 + hi*8 + i   (pre-scaled)
        const float* qp = q + ((size_t)n*QH + h*16 + col)*D + hi*8;
        #pragma unroll
        for (int kc = 0; kc < 4; ++kc) {
            float4 a = *(const float4*)(qp + kc*32);
            float4 b = *(const float4*)(qp + kc*32 + 4);
            short8 f;
            f[0] = (short)f2bf(a.x*sm_scale); f[1] = (short)f2bf(a.y*sm_scale);
            f[2] = (short)f2bf(a.z*sm_scale); f[3] = (short)f2bf(a.w*sm_scale);
            f[4] = (short)f2bf(b.x*sm_scale); f[5] = (short)f2bf(b.y*sm_scale);
            f[6] = (short)f2bf(b.z*sm_scale); f[7] = (short)f2bf(b.w*sm_scale);
            qf[rt][kc] = f;
        }
    }

    f32x4 oacc[2][8];
    #pragma unroll
    for (int rt = 0; rt < 2; ++rt)
        #pragma unroll
        for (int dt = 0; dt < 8; ++dt)
            oacc[rt][dt] = (f32x4){0.f, 0.f, 0.f, 0.f};
    float rmax[2][4], rsum[2][4];
    #pragma unroll
    for (int rt = 0; rt < 2; ++rt)
        #pragma unroll
        for (int j = 0; j < 4; ++j) { rmax[rt][j] = NEG_INF; rsum[rt][j] = 0.f; }

    const int nlast    = n0 + 15;
    const int mcnt_blk = (nlast >= 31) ? (((nlast - 31) >> 4) + 1) : 0;
    const int nch      = (mcnt_blk + 31) >> 5;

    for (int c = 0; c < nch; ++c) {
        const int m0 = c << 5;
        __syncthreads();
        // ---- stage ck (32 x 128) and cvT (128 x 32) chunks, bf16 ----
        {
            int r  = t >> 4, c8 = (t & 15) << 3;
            *(ushort8*)&ck_s[r][c8] =
                *(const ushort8*)&ckb[(((h << 9) + m0 + r) << 7) + c8];
            int dr = t >> 2, c8v = (t & 3) << 3;
            *(ushort8*)&cvT_s[dr][c8v] =
                *(const ushort8*)&cvbT[(((h << 7) + dr) << 9) + m0 + c8v];
        }
        __syncthreads();

        #pragma unroll
        for (int rt = 0; rt < 2; ++rt) {
            if (m0 >= mcnt[rt]) continue;

            // ---- QK^T: two 16-col m-tiles, K=128 over 4 chunks ----
            f32x4 s[2];
            #pragma unroll
            for (int mt = 0; mt < 2; ++mt) {
                f32x4 acc = (f32x4){0.f, 0.f, 0.f, 0.f};
                #pragma unroll
                for (int kc = 0; kc < 4; ++kc) {
                    short8 bfr = *(const short8*)&ck_s[mt*16 + col][kc*32 + hi*8];
                    acc = __builtin_amdgcn_mfma_f32_16x16x32_bf16(qf[rt][kc], bfr, acc, 0, 0, 0);
                }
                s[mt] = acc;
            }
            // ---- mask (uniform per row since all rows share n) ----
            const bool v0 = (m0 + col)      < mcnt[rt];
            const bool v1 = (m0 + 16 + col) < mcnt[rt];
            #pragma unroll
            for (int j = 0; j < 4; ++j) {
                s[0][j] = v0 ? s[0][j] : NEG_INF;
                s[1][j] = v1 ? s[1][j] : NEG_INF;
            }
            // ---- online softmax (row reduce across 16 lanes) ----
            float pj0[4], pj1[4];
            #pragma unroll
            for (int j = 0; j < 4; ++j) {
                float tm = fmaxf(s[0][j], s[1][j]);
                tm = fmaxf(tm, __shfl_xor(tm, 1));
                tm = fmaxf(tm, __shfl_xor(tm, 2));
                tm = fmaxf(tm, __shfl_xor(tm, 4));
                tm = fmaxf(tm, __shfl_xor(tm, 8));
                float nm = fmaxf(rmax[rt][j], tm);
                float sc = __expf(rmax[rt][j] - nm);   // first chunk: exp(-inf)=0
                float p0 = __expf(s[0][j] - nm);
                float p1 = __expf(s[1][j] - nm);
                float ps = p0 + p1;
                ps += __shfl_xor(ps, 1);
                ps += __shfl_xor(ps, 2);
                ps += __shfl_xor(ps, 4);
                ps += __shfl_xor(ps, 8);
                rsum[rt][j] = rsum[rt][j] * sc + ps;
                rmax[rt][j] = nm;
                pj0[j] = p0; pj1[j] = p1;
                #pragma unroll
                for (int dt = 0; dt < 8; ++dt) oacc[rt][dt][j] *= sc;
            }
            // ---- P -> LDS (transpose to A-frag layout), then PV ----
            unsigned short* pb = &p_s[wid*2 + rt][0][0];
            #pragma unroll
            for (int j = 0; j < 4; ++j) {
                pb[(hi*4 + j)*40 + col]      = f2bf(pj0[j]);
                pb[(hi*4 + j)*40 + 16 + col] = f2bf(pj1[j]);
            }
            asm volatile("s_waitcnt lgkmcnt(0)" ::: "memory");
            short8 pa = *(const short8*)&pb[col*40 + hi*8];
            #pragma unroll
            for (int dt = 0; dt < 8; ++dt) {
                short8 bv = *(const short8*)&cvT_s[dt*16 + col][hi*8];
                oacc[rt][dt] = __builtin_amdgcn_mfma_f32_16x16x32_bf16(pa, bv, oacc[rt][dt], 0, 0, 0);
            }
        }
    }

    // ---- epilogue: normalize, write o and lse ----
    #pragma unroll
    for (int rt = 0; rt < 2; ++rt) {
        const int n = nrow[rt];
        const bool valid = mcnt[rt] > 0;
        #pragma unroll
        for (int j = 0; j < 4; ++j) {
            const int g = hi*4 + j;
            float inv = valid ? (1.0f / rsum[rt][j]) : 0.0f;
            float* op = o + ((size_t)n*QH + h*16 + g)*D;
            #pragma unroll
            for (int dt = 0; dt < 8; ++dt)
                op[dt*16 + col] = oacc[rt][dt][j] * inv;
            if (col == 0) {
                float lv = valid ? (rmax[rt][j] + logf(rsum[rt][j])) : 0.0f;
                lse[(h*16 + g)*N_SEQ + n] = lv;
            }
        }
    }
}

extern "C" void kernel_launch(void* const* d_in, const int* in_sizes, int n_in,
                              void* d_out, int out_size, void* d_ws, size_t ws_size,
                              hipStream_t stream)
{
    const float* q      = (const float*)d_in[0];
    const float* k      = (const float*)d_in[1];
    const float* v      = (const float*)d_in[2];
    const float* w_key  = (const float*)d_in[3];
    const float* pe_key = (const float*)d_in[4];
    const float* w_val  = (const float*)d_in[5];
    const float* pe_val = (const float*)d_in[6];

    float* o   = (float*)d_out;                    // (1, 8192, 32, 128)
    float* lse = o + (size_t)N_SEQ * QH * D;       // (1, 32, 8192)
    float* ck  = lse + (size_t)QH * N_SEQ;         // (1, 511, 2, 128)

    unsigned short* ckb  = (unsigned short*)d_ws;  // [KH][512][128] bf16
    unsigned short* cvbT = ckb + (size_t)KH*MP*D;  // [KH][128][512] bf16

    compress_kernel<<<dim3(MP), dim3(256), 0, stream>>>(
        k, v, w_key, pe_key, w_val, pe_val, ck, ckb, cvbT);

    attn_kernel<<<dim3(N_SEQ/16, KH), dim3(512), 0, stream>>>(
        q, ckb, cvbT, o, lse);
}